// Round 4
// baseline (139.845 us; speedup 1.0000x reference)
//
#include <hip/hip_runtime.h>
#include <hip/hip_bf16.h>

typedef __attribute__((ext_vector_type(8))) short short8;
typedef __attribute__((ext_vector_type(4))) float floatx4;
typedef __attribute__((ext_vector_type(4))) unsigned int uintx4;

// accurate pack (used only in conv, off the hot path)
__device__ __forceinline__ unsigned pack2_bf16_rn(float a, float b) {
  __hip_bfloat162 h = __float22bfloat162_rn(make_float2(a, b));
  unsigned r;
  __builtin_memcpy(&r, &h, 4);
  return r;
}

// fast pack: +0x8000 (round-to-nearest, ties away; inputs finite) + byte perm.
// result = (bf16(b) << 16) | bf16(a)   -- 3 VALU ops total
__device__ __forceinline__ unsigned pack2_bf16_fast(float a, float b) {
  unsigned ua, ub;
  __builtin_memcpy(&ua, &a, 4);
  __builtin_memcpy(&ub, &b, 4);
  return __builtin_amdgcn_perm(ub + 0x8000u, ua + 0x8000u, 0x07060302u);
}

// tanh + Legendre P1..P8 -> 8-bf16 MFMA A-fragment. ~26 math + 12 pack VALU.
__device__ __forceinline__ short8 legendre_frag(float xv) {
  float e  = __builtin_amdgcn_exp2f(xv * 2.885390081777927f); // 2*log2(e)
  float t  = 1.0f - 2.0f * __builtin_amdgcn_rcpf(e + 1.0f);
  // P_k = u + c_k*(u - P_{k-2}), u = t*P_{k-1}, c_k=(k-1)/k  (3 ops/degree)
  float p1 = t;
  float u2 = t * p1,  w2 = u2 - 1.0f;        float p2 = fmaf(0.5f, w2, u2);
  float u3 = t * p2,  w3 = u3 - p1;          float p3 = fmaf(2.0f/3.0f, w3, u3);
  float u4 = t * p3,  w4 = u4 - p2;          float p4 = fmaf(0.75f, w4, u4);
  float u5 = t * p4,  w5 = u5 - p3;          float p5 = fmaf(0.8f, w5, u5);
  float u6 = t * p5,  w6 = u6 - p4;          float p6 = fmaf(5.0f/6.0f, w6, u6);
  float u7 = t * p6,  w7 = u7 - p5;          float p7 = fmaf(6.0f/7.0f, w7, u7);
  float u8 = t * p7,  w8 = u8 - p6;          float p8 = fmaf(7.0f/8.0f, w8, u8);
  union { unsigned u[4]; short8 s; } r;
  r.u[0] = pack2_bf16_fast(p1, p2);
  r.u[1] = pack2_bf16_fast(p3, p4);
  r.u[2] = pack2_bf16_fast(p5, p6);
  r.u[3] = pack2_bf16_fast(p7, p8);
  return r.s;
}

// ---- kernel 1: c_basis fp32 -> bf16, transposed to ws[i][o][d] (256 KB) ----
// coalesced writes (consecutive o -> contiguous 16B); reads served by L1/L2
__global__ void conv_kernel(const float* __restrict__ cb, unsigned short* __restrict__ ws) {
  int t = blockIdx.x * 256 + threadIdx.x;   // 0..16383
  int o = t & 63;
  int i = t >> 6;
  const floatx4* s = (const floatx4*)(cb + ((size_t)o * 256 + i) * 8);
  floatx4 v0 = s[0], v1 = s[1];
  uintx4 w;
  w.x = pack2_bf16_rn(v0.x, v0.y);
  w.y = pack2_bf16_rn(v0.z, v0.w);
  w.z = pack2_bf16_rn(v1.x, v1.y);
  w.w = pack2_bf16_rn(v1.z, v1.w);
  *(uintx4*)(ws + (size_t)i * 512 + o * 8) = w;
}

// ---- kernel 2: barrier-free. 128 threads (2 waves), 64 rows/block. ----
// No LDS. B-frags + x values loaded direct from global (L1/L2-resident ws),
// 1-iteration register prefetch pipeline keeps loads in flight continuously.
__global__ __launch_bounds__(128, 2) void kan_kernel(
    const float* __restrict__ x, const unsigned short* __restrict__ ws,
    const float* __restrict__ bias, float* __restrict__ y) {
  const int tid  = threadIdx.x;
  const int wid  = tid >> 6;    // 0..1
  const int lane = tid & 63;
  const int m    = lane & 15;
  const int q    = lane >> 4;
  const int row_block = blockIdx.x * 64;

  floatx4 acc[2][4];
#pragma unroll
  for (int a = 0; a < 2; ++a)
#pragma unroll
    for (int nt = 0; nt < 4; ++nt) acc[a][nt] = (floatx4){0.f, 0.f, 0.f, 0.f};

  // lane's A-frag at K-step s covers i = s*4 + q, rows r0g and r0g+16
  const int r0g = row_block + wid * 32 + m;
  const float* xp0 = x + (size_t)r0g * 256 + q;       // + s*4 per step
  const float* xp1 = xp0 + 16 * 256;
  // B-frag: ws[i=s*4+q][o=nt*16+m][d=0..7] -> shorts: s*2048 + q*512 + nt*128 + m*8
  const unsigned short* bp = ws + q * 512 + m * 8;

  // prologue: prefetch s=0
  short8 fbN[4];
#pragma unroll
  for (int nt = 0; nt < 4; ++nt) fbN[nt] = *(const short8*)(bp + nt * 128);
  float xvN0 = xp0[0];
  float xvN1 = xp1[0];

#pragma unroll 2
  for (int s = 0; s < 64; ++s) {
    short8 fb0 = fbN[0], fb1 = fbN[1], fb2 = fbN[2], fb3 = fbN[3];
    float xv0 = xvN0, xv1 = xvN1;
    // prefetch s+1 (clamped; s=63 harmlessly reloads s=63 from L1)
    int sn = (s < 63) ? (s + 1) : 63;
#pragma unroll
    for (int nt = 0; nt < 4; ++nt)
      fbN[nt] = *(const short8*)(bp + (size_t)sn * 2048 + nt * 128);
    xvN0 = xp0[sn * 4];
    xvN1 = xp1[sn * 4];

    short8 fa0 = legendre_frag(xv0);
    short8 fa1 = legendre_frag(xv1);
    acc[0][0] = __builtin_amdgcn_mfma_f32_16x16x32_bf16(fa0, fb0, acc[0][0], 0, 0, 0);
    acc[1][0] = __builtin_amdgcn_mfma_f32_16x16x32_bf16(fa1, fb0, acc[1][0], 0, 0, 0);
    acc[0][1] = __builtin_amdgcn_mfma_f32_16x16x32_bf16(fa0, fb1, acc[0][1], 0, 0, 0);
    acc[1][1] = __builtin_amdgcn_mfma_f32_16x16x32_bf16(fa1, fb1, acc[1][1], 0, 0, 0);
    acc[0][2] = __builtin_amdgcn_mfma_f32_16x16x32_bf16(fa0, fb2, acc[0][2], 0, 0, 0);
    acc[1][2] = __builtin_amdgcn_mfma_f32_16x16x32_bf16(fa1, fb2, acc[1][2], 0, 0, 0);
    acc[0][3] = __builtin_amdgcn_mfma_f32_16x16x32_bf16(fa0, fb3, acc[0][3], 0, 0, 0);
    acc[1][3] = __builtin_amdgcn_mfma_f32_16x16x32_bf16(fa1, fb3, acc[1][3], 0, 0, 0);
  }

  // epilogue: D[row=(q*4+reg)][col=m], add bias  (layout verified rounds 1-3)
  float bv[4];
#pragma unroll
  for (int nt = 0; nt < 4; ++nt) bv[nt] = bias[nt * 16 + m];
#pragma unroll
  for (int a = 0; a < 2; ++a) {
    int gr0 = row_block + wid * 32 + a * 16 + q * 4;
#pragma unroll
    for (int nt = 0; nt < 4; ++nt) {
#pragma unroll
      for (int r = 0; r < 4; ++r) {
        y[(size_t)(gr0 + r) * 64 + nt * 16 + m] = acc[a][nt][r] + bv[nt];
      }
    }
  }
}

extern "C" void kernel_launch(void* const* d_in, const int* in_sizes, int n_in,
                              void* d_out, int out_size, void* d_ws, size_t ws_size,
                              hipStream_t stream) {
  const float* x    = (const float*)d_in[0];
  const float* cb   = (const float*)d_in[1];
  const float* bias = (const float*)d_in[2];
  float* y = (float*)d_out;
  unsigned short* ws = (unsigned short*)d_ws;
  int batch = in_sizes[0] / 256;  // 65536
  hipLaunchKernelGGL(conv_kernel, dim3(64), dim3(256), 0, stream, cb, ws);
  hipLaunchKernelGGL(kan_kernel, dim3(batch / 64), dim3(128), 0, stream, x, ws, bias, y);
}